// Round 2
// baseline (655.253 us; speedup 1.0000x reference)
//
#include <hip/hip_runtime.h>
#include <math.h>

#define BDIM 2
#define SDIM 4096
#define DMODEL 512
#define NHEAD 8
#define DHEAD 64
#define MROWS (BDIM * SDIM)  // 8192

typedef __attribute__((ext_vector_type(8))) short short8;
typedef __attribute__((ext_vector_type(4))) float f32x4;

#define MFMA16(a, b, c) __builtin_amdgcn_mfma_f32_16x16x32_bf16((a), (b), (c), 0, 0, 0)
#define EXP2F(x) __builtin_amdgcn_exp2f(x)

#define SCALE2 0.18033688011112042f  // 0.125 * log2(e)
#define MASKMUL -1.442695040e9f      // -1e9 * log2(e)
#define M0C 16.0f                    // fixed softmax shift (2^-M0 cancels in O/l)

#define GLOAD_LDS16(g, l)                                                     \
  __builtin_amdgcn_global_load_lds(                                           \
      (const __attribute__((address_space(1))) void*)(g),                     \
      (__attribute__((address_space(3))) void*)(l), 16, 0, 0)

// Truncation split: x = h + l with h = top 16 bits (exact subtraction).
__device__ inline void bf16_split(float x, short& h, short& l) {
  unsigned u = __float_as_uint(x);
  h = (short)(u >> 16);
  float hf = __uint_as_float(u & 0xffff0000u);
  l = (short)(__float_as_uint(x - hf) >> 16);
}

// ---------------------------------------------------------------------------
// One-shot weight prep: W[k][n] fp32 -> Wt_h[n][k], Wt_l[n][k] bf16 h/l.
// ---------------------------------------------------------------------------
__global__ __launch_bounds__(256) void wsplit_kernel(
    const float* __restrict__ W0, const float* __restrict__ W1,
    const float* __restrict__ W2, const float* __restrict__ W3,
    short* __restrict__ T0h, short* __restrict__ T0l, short* __restrict__ T1h,
    short* __restrict__ T1l, short* __restrict__ T2h, short* __restrict__ T2l,
    short* __restrict__ T3h, short* __restrict__ T3l) {
  __shared__ short Th[64 * 72], Tl[64 * 72];
  const int tid = threadIdx.x;
  const int k0 = blockIdx.x * 64;
  const int n0 = blockIdx.y * 64;
  const int z = blockIdx.z;
  const float* W = (z == 0) ? W0 : (z == 1) ? W1 : (z == 2) ? W2 : W3;
  short* Oh = (z == 0) ? T0h : (z == 1) ? T1h : (z == 2) ? T2h : T3h;
  short* Ol = (z == 0) ? T0l : (z == 1) ? T1l : (z == 2) ? T2l : T3l;

  {
    const int r = tid >> 2;
    const int c16 = (tid & 3) * 16;
    short8 h0, h1, l0, l1;
#pragma unroll
    for (int g = 0; g < 2; g++) {
      const f32x4 a = *(const f32x4*)(W + (size_t)(k0 + r) * DMODEL + n0 + c16 + g * 8);
      const f32x4 b = *(const f32x4*)(W + (size_t)(k0 + r) * DMODEL + n0 + c16 + g * 8 + 4);
      short8& hh = g ? h1 : h0;
      short8& ll = g ? l1 : l0;
#pragma unroll
      for (int j = 0; j < 4; j++) {
        short x, y;
        bf16_split(a[j], x, y);
        hh[j] = x;
        ll[j] = y;
        bf16_split(b[j], x, y);
        hh[4 + j] = x;
        ll[4 + j] = y;
      }
    }
    *(short8*)&Th[r * 72 + c16] = h0;
    *(short8*)&Th[r * 72 + c16 + 8] = h1;
    *(short8*)&Tl[r * 72 + c16] = l0;
    *(short8*)&Tl[r * 72 + c16 + 8] = l1;
  }
  __syncthreads();
  {
    const int n = tid >> 2;
    const int kc = (tid & 3) * 16;
    short8 h0, h1, l0, l1;
#pragma unroll
    for (int i = 0; i < 8; i++) {
      h0[i] = Th[(kc + i) * 72 + n];
      h1[i] = Th[(kc + 8 + i) * 72 + n];
      l0[i] = Tl[(kc + i) * 72 + n];
      l1[i] = Tl[(kc + 8 + i) * 72 + n];
    }
    short* dh = Oh + (size_t)(n0 + n) * DMODEL + k0 + kc;
    short* dl = Ol + (size_t)(n0 + n) * DMODEL + k0 + kc;
    *(short8*)dh = h0;
    *(short8*)(dh + 8) = h1;
    *(short8*)dl = l0;
    *(short8*)(dl + 8) = l1;
  }
}

// ---------------------------------------------------------------------------
// MFMA bf16x3 GEMM: out[M,512] = X[M,512](fp32) @ Wt(split)^T + bias.
// BM=64, BN=256, BK=32, 512 thr = 8 waves (2Mx4N), wave tile 32x64.
// A staged as RAW FP32 via global_load_lds (same bytes as h+l bf16) and
// split to bf16 h/l in registers after the ds_read — no separate xsplit
// pass, no pre-split activation buffers. B (weights) pre-split by wsplit.
// LDS double-buffered (80 KB). MODE 0: fp32 out. MODE 1: split h/l out
// in [B,H,S,D].
// ---------------------------------------------------------------------------
template <int MODE>
__global__ __launch_bounds__(512, 2) void proj3_kernel(
    const float* __restrict__ X, const short* __restrict__ Wth,
    const short* __restrict__ Wtl, const float* __restrict__ bias,
    float* __restrict__ out, short* __restrict__ oh, short* __restrict__ ol) {
  // per buffer (shorts): Af32[64*32 floats]=4096 | Bh[256*32]=8192 | Bl=8192
  __shared__ short L[2 * 20480];  // 80 KB
  const int tid = threadIdx.x;
  const int lane = tid & 63;
  const int w = tid >> 6;  // 0..7
  const int lane15 = lane & 15;
  const int quad = lane >> 4;
  const int m0 = blockIdx.x * 64;
  const int n0 = blockIdx.y * 256;
  const int wm = (w >> 2) * 32;
  const int wn = (w & 3) * 64;

  // Staging: 2560 16B-chunks/step, 5 per wave. idx<8 -> A (fp32),
  // idx>=8 -> B (bf16 h/l). Per-chunk K-step stride differs (128B vs 64B).
  const char* gp[5];
  int stepb[5], ldso[5];
#pragma unroll
  for (int i = 0; i < 5; i++) {
    const int idx = w * 5 + i;
    if (idx < 8) {  // A: fp32 rows, 8 chunks of 4 floats per 32-k row
      const int g = idx * 64 + lane;
      gp[i] = (const char*)(X + (size_t)(m0 + (g >> 3)) * DMODEL + (g & 7) * 4);
      stepb[i] = 128;
    } else {  // B: rows of Wth/Wtl, 4 chunks of 8 shorts per 32-k row
      const int gg = idx * 64 + lane - 512;
      const short* src = (gg < 1024) ? Wth : Wtl;
      const int a = gg & 1023;
      gp[i] = (const char*)(src + (size_t)(n0 + (a >> 2)) * DMODEL + (a & 3) * 8);
      stepb[i] = 64;
    }
    ldso[i] = idx * 512;  // shorts; wave-uniform
  }

  f32x4 c[2][4];
#pragma unroll
  for (int mt = 0; mt < 2; mt++)
#pragma unroll
    for (int nt = 0; nt < 4; nt++) c[mt][nt] = (f32x4){0.f, 0.f, 0.f, 0.f};

  constexpr int NT = DMODEL / 32;  // 16 K-steps

  // prologue: issue loads for t=0 into buffer 0
#pragma unroll
  for (int i = 0; i < 5; i++) GLOAD_LDS16(gp[i], &L[ldso[i]]);

  for (int t = 0; t < NT; t++) {
    __syncthreads();  // tile t resident; buf^1 free of readers
    if (t + 1 < NT) {
      short* dst = &L[((t + 1) & 1) * 20480];
#pragma unroll
      for (int i = 0; i < 5; i++)
        GLOAD_LDS16(gp[i] + (t + 1) * stepb[i], dst + ldso[i]);
    }
    const short* buf = &L[(t & 1) * 20480];
    const float* Af = (const float*)buf;
    short8 ah[2], al[2], bh[4], bl[4];
#pragma unroll
    for (int mt = 0; mt < 2; mt++) {
      const int r = wm + mt * 16 + lane15;
      const f32x4 a0 = *(const f32x4*)&Af[r * 32 + quad * 8];
      const f32x4 a1 = *(const f32x4*)&Af[r * 32 + quad * 8 + 4];
#pragma unroll
      for (int j = 0; j < 4; j++) {
        short x, y;
        bf16_split(a0[j], x, y);
        ah[mt][j] = x;
        al[mt][j] = y;
        bf16_split(a1[j], x, y);
        ah[mt][4 + j] = x;
        al[mt][4 + j] = y;
      }
    }
#pragma unroll
    for (int nt = 0; nt < 4; nt++) {
      const int r = wn + nt * 16 + lane15;
      bh[nt] = *(const short8*)&buf[4096 + r * 32 + quad * 8];
      bl[nt] = *(const short8*)&buf[12288 + r * 32 + quad * 8];
    }
    __builtin_amdgcn_s_setprio(1);
#pragma unroll
    for (int mt = 0; mt < 2; mt++)
#pragma unroll
      for (int nt = 0; nt < 4; nt++) {
        c[mt][nt] = MFMA16(ah[mt], bh[nt], c[mt][nt]);
        c[mt][nt] = MFMA16(ah[mt], bl[nt], c[mt][nt]);
        c[mt][nt] = MFMA16(al[mt], bh[nt], c[mt][nt]);
      }
    __builtin_amdgcn_s_setprio(0);
  }

  // ---- epilogue ----
#pragma unroll
  for (int nt = 0; nt < 4; nt++) {
    const int n = n0 + wn + nt * 16 + lane15;
    const float bb = bias[n];
#pragma unroll
    for (int mt = 0; mt < 2; mt++)
#pragma unroll
      for (int r = 0; r < 4; r++) {
        const int m = m0 + wm + mt * 16 + quad * 4 + r;
        const float val = c[mt][nt][r] + bb;
        if (MODE == 1) {
          const int bidx = m >> 12;
          const int s = m & 4095;
          const int hh = n >> 6;
          const int d = n & 63;
          const size_t off =
              ((size_t)(bidx * NHEAD + hh) * SDIM + s) * DHEAD + d;
          short x, y;
          bf16_split(val, x, y);
          oh[off] = x;
          ol[off] = y;
        } else {
          out[(size_t)m * DMODEL + n] = val;
        }
      }
  }
}

// ---------------------------------------------------------------------------
// V transpose: [B,H,S,D] h/l shorts -> [B,H,D,S]. 64x64 tiles via LDS.
// ---------------------------------------------------------------------------
__global__ __launch_bounds__(256) void vtrans_kernel(
    const short* __restrict__ vh, const short* __restrict__ vl,
    short* __restrict__ vth, short* __restrict__ vtl) {
  __shared__ short Th[64 * 72], Tl[64 * 72];
  const int tid = threadIdx.x;
  const int s0 = blockIdx.x * 64;
  const int h = blockIdx.y;
  const int b = blockIdx.z;
  const size_t base = (size_t)(b * NHEAD + h) * SDIM * DHEAD;

  {
    const int s = tid >> 2;
    const int c = tid & 3;
    const short* srcH = vh + base + (size_t)(s0 + s) * DHEAD + c * 16;
    const short* srcL = vl + base + (size_t)(s0 + s) * DHEAD + c * 16;
    *(short8*)&Th[s * 72 + c * 16] = *(const short8*)srcH;
    *(short8*)&Th[s * 72 + c * 16 + 8] = *(const short8*)(srcH + 8);
    *(short8*)&Tl[s * 72 + c * 16] = *(const short8*)srcL;
    *(short8*)&Tl[s * 72 + c * 16 + 8] = *(const short8*)(srcL + 8);
  }
  __syncthreads();
  {
    const int d = tid & 63;
    const int cw = tid >> 6;
    short8 a0, a1, b0, b1;
#pragma unroll
    for (int i = 0; i < 8; i++) {
      a0[i] = Th[(cw * 16 + i) * 72 + d];
      a1[i] = Th[(cw * 16 + 8 + i) * 72 + d];
      b0[i] = Tl[(cw * 16 + i) * 72 + d];
      b1[i] = Tl[(cw * 16 + 8 + i) * 72 + d];
    }
    short* dstH = vth + base + (size_t)d * SDIM + s0 + cw * 16;
    short* dstL = vtl + base + (size_t)d * SDIM + s0 + cw * 16;
    *(short8*)dstH = a0;
    *(short8*)(dstH + 8) = a1;
    *(short8*)dstL = b0;
    *(short8*)(dstL + 8) = b1;
  }
}

// ---------------------------------------------------------------------------
// Flash attention, bf16x3 MFMA, fixed-shift softmax.
// This round: NO K/V LDS staging — K/V fragments load straight from L2
// (K/V per head = 2 MB, L2-resident; staging them was pure overhead and
// the source of the 2.9e7 bank-conflict cycles). LDS holds only Ps, which
// is wave-private -> ZERO barriers in the k-loop; waves run free.
// XCD-aware swizzle clusters 2 heads per XCD for L2 locality.
// ctx written as fp32 (output projection consumes fp32 directly).
// ---------------------------------------------------------------------------
#define PP 68

__global__ __launch_bounds__(256, 2) void flash_attn_kernel(
    const short* __restrict__ qhh, const short* __restrict__ qhl,
    const short* __restrict__ khh, const short* __restrict__ khl,
    const short* __restrict__ vth, const short* __restrict__ vtl,
    const float* __restrict__ mask, float* __restrict__ ctx) {
  __shared__ float Ps[128 * PP];  // 34.8 KB, wave-private rows

  const int tid = threadIdx.x;
  const int lane = tid & 63;
  const int w = tid >> 6;
  const int lane15 = lane & 15;
  const int quad = lane >> 4;

  // Bijective XCD swizzle (nwg=512, 512%8==0): ids i, i+8, ... (one XCD)
  // get contiguous work chunks -> each XCD sees 2 heads (4 MB K/V h+l).
  const int bid = blockIdx.x + (SDIM / 128) * (blockIdx.y + NHEAD * blockIdx.z);
  const int sw = (bid & 7) * 64 + (bid >> 3);
  const int q0 = (sw & 31) * 128;
  const int h = (sw >> 5) & 7;
  const int b = sw >> 8;

  const size_t base = (size_t)(b * NHEAD + h) * SDIM * DHEAD;
  const short* Qh = qhh + base;
  const short* Ql = qhl + base;
  const short* Kh = khh + base;
  const short* Kl = khl + base;
  const short* Vh = vth + base;  // [D][S]
  const short* Vl = vtl + base;
  const float* mb = mask + (size_t)b * SDIM;

  short8 qfh[2][2], qfl[2][2];
#pragma unroll
  for (int mt = 0; mt < 2; mt++) {
    const size_t row = q0 + w * 32 + mt * 16 + lane15;
#pragma unroll
    for (int ks = 0; ks < 2; ks++) {
      qfh[mt][ks] = *(const short8*)(Qh + row * DHEAD + ks * 32 + quad * 8);
      qfl[mt][ks] = *(const short8*)(Ql + row * DHEAD + ks * 32 + quad * 8);
    }
  }

  f32x4 o[2][4];
#pragma unroll
  for (int mt = 0; mt < 2; mt++)
#pragma unroll
    for (int dt = 0; dt < 4; dt++) o[mt][dt] = (f32x4){0.f, 0.f, 0.f, 0.f};
  float lr[2][4];
#pragma unroll
  for (int mt = 0; mt < 2; mt++)
#pragma unroll
    for (int r = 0; r < 4; r++) lr[mt][r] = 0.f;

  short8 onesb;
#pragma unroll
  for (int j = 0; j < 8; j++) onesb[j] = (short)0x3F80;  // bf16 1.0

  for (int kt = 0; kt < SDIM / 64; kt++) {
    const int k0 = kt * 64;

    // K fragments straight from L2 (16 rows x 128 B contiguous per instr).
    short8 kh8[4][2], kl8[4][2];
#pragma unroll
    for (int nt = 0; nt < 4; nt++)
#pragma unroll
      for (int ks = 0; ks < 2; ks++) {
        const size_t ko =
            (size_t)(k0 + nt * 16 + lane15) * DHEAD + ks * 32 + quad * 8;
        kh8[nt][ks] = *(const short8*)(Kh + ko);
        kl8[nt][ks] = *(const short8*)(Kl + ko);
      }
    float mv[4];
#pragma unroll
    for (int nt = 0; nt < 4; nt++)
      mv[nt] = fmaf(mb[k0 + nt * 16 + lane15], MASKMUL, -M0C);

    __builtin_amdgcn_s_setprio(1);
#pragma unroll
    for (int mt = 0; mt < 2; mt++)
#pragma unroll
      for (int nt = 0; nt < 4; nt++) {
        f32x4 acc = (f32x4){0.f, 0.f, 0.f, 0.f};
#pragma unroll
        for (int ks = 0; ks < 2; ks++) {
          acc = MFMA16(qfh[mt][ks], kh8[nt][ks], acc);
          acc = MFMA16(qfh[mt][ks], kl8[nt][ks], acc);
          acc = MFMA16(qfl[mt][ks], kh8[nt][ks], acc);
        }
#pragma unroll
        for (int r = 0; r < 4; r++) {
          const float p = EXP2F(fmaf(acc[r], SCALE2, mv[nt]));
          Ps[(w * 32 + mt * 16 + quad * 4 + r) * PP + nt * 16 + lane15] = p;
        }
      }
    __builtin_amdgcn_s_setprio(0);

    // V fragments issue now; they land under the P-split VALU work.
    short8 vh8[4][2], vl8[4][2];
#pragma unroll
    for (int dt = 0; dt < 4; dt++)
#pragma unroll
      for (int kf = 0; kf < 2; kf++) {
        const size_t vo =
            (size_t)(dt * 16 + lane15) * SDIM + k0 + kf * 32 + quad * 8;
        vh8[dt][kf] = *(const short8*)(Vh + vo);
        vl8[dt][kf] = *(const short8*)(Vl + vo);
      }

    // P split (wave-private LDS: compiler inserts lgkmcnt, no barrier).
    short8 pah[2][2], pal[2][2];
#pragma unroll
    for (int mt = 0; mt < 2; mt++)
#pragma unroll
      for (int kf = 0; kf < 2; kf++) {
        const float* pr =
            &Ps[(w * 32 + mt * 16 + lane15) * PP + kf * 32 + quad * 8];
        const f32x4 p0 = *(const f32x4*)pr;
        const f32x4 p1 = *(const f32x4*)(pr + 4);
        short8 ph, pl;
#pragma unroll
        for (int j = 0; j < 4; j++) {
          short hh, ll;
          bf16_split(p0[j], hh, ll);
          ph[j] = hh;
          pl[j] = ll;
        }
#pragma unroll
        for (int j = 0; j < 4; j++) {
          short hh, ll;
          bf16_split(p1[j], hh, ll);
          ph[4 + j] = hh;
          pl[4 + j] = ll;
        }
        pah[mt][kf] = ph;
        pal[mt][kf] = pl;
      }

    __builtin_amdgcn_s_setprio(1);
#pragma unroll
    for (int mt = 0; mt < 2; mt++) {
      f32x4 racc = (f32x4){0.f, 0.f, 0.f, 0.f};
#pragma unroll
      for (int kf = 0; kf < 2; kf++) {
        racc = MFMA16(pah[mt][kf], onesb, racc);
        racc = MFMA16(pal[mt][kf], onesb, racc);
      }
#pragma unroll
      for (int r = 0; r < 4; r++) lr[mt][r] += racc[r];
    }

#pragma unroll
    for (int dt = 0; dt < 4; dt++)
#pragma unroll
      for (int kf = 0; kf < 2; kf++) {
#pragma unroll
        for (int mt = 0; mt < 2; mt++) {
          o[mt][dt] = MFMA16(pah[mt][kf], vh8[dt][kf], o[mt][dt]);
          o[mt][dt] = MFMA16(pah[mt][kf], vl8[dt][kf], o[mt][dt]);
          o[mt][dt] = MFMA16(pal[mt][kf], vh8[dt][kf], o[mt][dt]);
        }
      }
    __builtin_amdgcn_s_setprio(0);
  }

  float inv[2][4];
#pragma unroll
  for (int mt = 0; mt < 2; mt++)
#pragma unroll
    for (int r = 0; r < 4; r++) inv[mt][r] = 1.f / lr[mt][r];
#pragma unroll
  for (int mt = 0; mt < 2; mt++)
#pragma unroll
    for (int dt = 0; dt < 4; dt++)
#pragma unroll
      for (int r = 0; r < 4; r++) {
        const int q = q0 + w * 32 + mt * 16 + quad * 4 + r;
        const int col = h * DHEAD + dt * 16 + lane15;
        ctx[((size_t)b * SDIM + q) * DMODEL + col] = o[mt][dt][r] * inv[mt][r];
      }
}

// ---------------------------------------------------------------------------
extern "C" void kernel_launch(void* const* d_in, const int* in_sizes, int n_in,
                              void* d_out, int out_size, void* d_ws,
                              size_t ws_size, hipStream_t stream) {
  const float* q = (const float*)d_in[0];
  const float* k = (const float*)d_in[1];
  const float* v = (const float*)d_in[2];
  const float* mask = (const float*)d_in[3];
  const float* Wq = (const float*)d_in[4];
  const float* bq = (const float*)d_in[5];
  const float* Wk = (const float*)d_in[6];
  const float* bk = (const float*)d_in[7];
  const float* Wv = (const float*)d_in[8];
  const float* bv = (const float*)d_in[9];
  const float* Wo = (const float*)d_in[10];
  const float* bo = (const float*)d_in[11];
  float* out = (float*)d_out;

  char* W = (char*)d_ws;
  const size_t SZB = (size_t)MROWS * DMODEL * sizeof(short);  // 8 MB
  short* q_h = (short*)(W + 0 * SZB);
  short* q_l = (short*)(W + 1 * SZB);
  short* k_h = (short*)(W + 2 * SZB);
  short* k_l = (short*)(W + 3 * SZB);
  short* v_h = (short*)(W + 4 * SZB);
  short* v_l = (short*)(W + 5 * SZB);
  short* vt_h = (short*)(W + 6 * SZB);
  short* vt_l = (short*)(W + 7 * SZB);
  // ctx (fp32, 16 MB) aliases v_h/v_l — dead after vtrans.
  float* ctx = (float*)(W + 4 * SZB);
  const size_t WSZ = (size_t)DMODEL * DMODEL * sizeof(short);  // 512 KB
  char* WT = W + 8 * SZB;
  short* wtq_h = (short*)(WT + 0 * WSZ);
  short* wtq_l = (short*)(WT + 1 * WSZ);
  short* wtk_h = (short*)(WT + 2 * WSZ);
  short* wtk_l = (short*)(WT + 3 * WSZ);
  short* wtv_h = (short*)(WT + 4 * WSZ);
  short* wtv_l = (short*)(WT + 5 * WSZ);
  short* wto_h = (short*)(WT + 6 * WSZ);
  short* wto_l = (short*)(WT + 7 * WSZ);

  wsplit_kernel<<<dim3(DMODEL / 64, DMODEL / 64, 4), 256, 0, stream>>>(
      Wq, Wk, Wv, Wo, wtq_h, wtq_l, wtk_h, wtk_l, wtv_h, wtv_l, wto_h, wto_l);

  const dim3 gp2(MROWS / 64, DMODEL / 256);  // (128, 2)

  proj3_kernel<1><<<gp2, 512, 0, stream>>>(q, wtq_h, wtq_l, bq, nullptr, q_h,
                                           q_l);
  proj3_kernel<1><<<gp2, 512, 0, stream>>>(k, wtk_h, wtk_l, bk, nullptr, k_h,
                                           k_l);
  proj3_kernel<1><<<gp2, 512, 0, stream>>>(v, wtv_h, wtv_l, bv, nullptr, v_h,
                                           v_l);

  vtrans_kernel<<<dim3(SDIM / 64, NHEAD, BDIM), 256, 0, stream>>>(v_h, v_l,
                                                                  vt_h, vt_l);

  flash_attn_kernel<<<dim3(SDIM / 128, NHEAD, BDIM), 256, 0, stream>>>(
      q_h, q_l, k_h, k_l, vt_h, vt_l, mask, ctx);

  proj3_kernel<0><<<gp2, 512, 0, stream>>>(ctx, wto_h, wto_l, bo, out, nullptr,
                                           nullptr);
}

// Round 3
// 446.796 us; speedup vs baseline: 1.4666x; 1.4666x over previous
//
#include <hip/hip_runtime.h>
#include <math.h>

#define BDIM 2
#define SDIM 4096
#define DMODEL 512
#define NHEAD 8
#define DHEAD 64
#define MROWS (BDIM * SDIM)  // 8192

typedef __attribute__((ext_vector_type(8))) short short8;
typedef __attribute__((ext_vector_type(4))) float f32x4;

#define MFMA16(a, b, c) __builtin_amdgcn_mfma_f32_16x16x32_bf16((a), (b), (c), 0, 0, 0)
#define EXP2F(x) __builtin_amdgcn_exp2f(x)

#define SCALE2 0.18033688011112042f  // 0.125 * log2(e)
#define MASKMUL -1.442695040e9f      // -1e9 * log2(e)
#define M0C 16.0f                    // fixed softmax shift (2^-M0 cancels in O/l)

#define GLOAD_LDS16(g, l)                                                     \
  __builtin_amdgcn_global_load_lds(                                           \
      (const __attribute__((address_space(1))) void*)(g),                     \
      (__attribute__((address_space(3))) void*)(l), 16, 0, 0)

// Truncation split: x = h + l with h = top 16 bits (exact subtraction).
__device__ inline void bf16_split(float x, short& h, short& l) {
  unsigned u = __float_as_uint(x);
  h = (short)(u >> 16);
  float hf = __uint_as_float(u & 0xffff0000u);
  l = (short)(__float_as_uint(x - hf) >> 16);
}

// ---------------------------------------------------------------------------
// One-shot weight prep: W[k][n] fp32 -> Wt_h[n][k], Wt_l[n][k] bf16 h/l.
// ---------------------------------------------------------------------------
__global__ __launch_bounds__(256) void wsplit_kernel(
    const float* __restrict__ W0, const float* __restrict__ W1,
    const float* __restrict__ W2, const float* __restrict__ W3,
    short* __restrict__ T0h, short* __restrict__ T0l, short* __restrict__ T1h,
    short* __restrict__ T1l, short* __restrict__ T2h, short* __restrict__ T2l,
    short* __restrict__ T3h, short* __restrict__ T3l) {
  __shared__ short Th[64 * 72], Tl[64 * 72];
  const int tid = threadIdx.x;
  const int k0 = blockIdx.x * 64;
  const int n0 = blockIdx.y * 64;
  const int z = blockIdx.z;
  const float* W = (z == 0) ? W0 : (z == 1) ? W1 : (z == 2) ? W2 : W3;
  short* Oh = (z == 0) ? T0h : (z == 1) ? T1h : (z == 2) ? T2h : T3h;
  short* Ol = (z == 0) ? T0l : (z == 1) ? T1l : (z == 2) ? T2l : T3l;

  {
    const int r = tid >> 2;
    const int c16 = (tid & 3) * 16;
    short8 h0, h1, l0, l1;
#pragma unroll
    for (int g = 0; g < 2; g++) {
      const f32x4 a = *(const f32x4*)(W + (size_t)(k0 + r) * DMODEL + n0 + c16 + g * 8);
      const f32x4 b = *(const f32x4*)(W + (size_t)(k0 + r) * DMODEL + n0 + c16 + g * 8 + 4);
      short8& hh = g ? h1 : h0;
      short8& ll = g ? l1 : l0;
#pragma unroll
      for (int j = 0; j < 4; j++) {
        short x, y;
        bf16_split(a[j], x, y);
        hh[j] = x;
        ll[j] = y;
        bf16_split(b[j], x, y);
        hh[4 + j] = x;
        ll[4 + j] = y;
      }
    }
    *(short8*)&Th[r * 72 + c16] = h0;
    *(short8*)&Th[r * 72 + c16 + 8] = h1;
    *(short8*)&Tl[r * 72 + c16] = l0;
    *(short8*)&Tl[r * 72 + c16 + 8] = l1;
  }
  __syncthreads();
  {
    const int n = tid >> 2;
    const int kc = (tid & 3) * 16;
    short8 h0, h1, l0, l1;
#pragma unroll
    for (int i = 0; i < 8; i++) {
      h0[i] = Th[(kc + i) * 72 + n];
      h1[i] = Th[(kc + 8 + i) * 72 + n];
      l0[i] = Tl[(kc + i) * 72 + n];
      l1[i] = Tl[(kc + 8 + i) * 72 + n];
    }
    short* dh = Oh + (size_t)(n0 + n) * DMODEL + k0 + kc;
    short* dl = Ol + (size_t)(n0 + n) * DMODEL + k0 + kc;
    *(short8*)dh = h0;
    *(short8*)(dh + 8) = h1;
    *(short8*)dl = l0;
    *(short8*)(dl + 8) = l1;
  }
}

// ---------------------------------------------------------------------------
// MFMA bf16x3 GEMM: out[M,512] = X[M,512](fp32) @ Wt(split)^T + bias.
// BM=64, BN=256, BK=32, 512 thr = 8 waves (2Mx4N), wave tile 32x64.
// A staged as RAW FP32 via global_load_lds and split in-register after the
// ds_read. B (weights) pre-split by wsplit. LDS double-buffered (80 KB).
// MODE 0: fp32 out. MODE 1: split h/l out in [B,H,S,D].
// ---------------------------------------------------------------------------
template <int MODE>
__global__ __launch_bounds__(512, 2) void proj3_kernel(
    const float* __restrict__ X, const short* __restrict__ Wth,
    const short* __restrict__ Wtl, const float* __restrict__ bias,
    float* __restrict__ out, short* __restrict__ oh, short* __restrict__ ol) {
  // per buffer (shorts): Af32[64*32 floats]=4096 | Bh[256*32]=8192 | Bl=8192
  __shared__ short L[2 * 20480];  // 80 KB
  const int tid = threadIdx.x;
  const int lane = tid & 63;
  const int w = tid >> 6;  // 0..7
  const int lane15 = lane & 15;
  const int quad = lane >> 4;
  const int m0 = blockIdx.x * 64;
  const int n0 = blockIdx.y * 256;
  const int wm = (w >> 2) * 32;
  const int wn = (w & 3) * 64;

  // Staging: 2560 16B-chunks/step, 5 per wave. idx<8 -> A (fp32),
  // idx>=8 -> B (bf16 h/l). Per-chunk K-step stride differs (128B vs 64B).
  const char* gp[5];
  int stepb[5], ldso[5];
#pragma unroll
  for (int i = 0; i < 5; i++) {
    const int idx = w * 5 + i;
    if (idx < 8) {  // A: fp32 rows, 8 chunks of 4 floats per 32-k row
      const int g = idx * 64 + lane;
      gp[i] = (const char*)(X + (size_t)(m0 + (g >> 3)) * DMODEL + (g & 7) * 4);
      stepb[i] = 128;
    } else {  // B: rows of Wth/Wtl, 4 chunks of 8 shorts per 32-k row
      const int gg = idx * 64 + lane - 512;
      const short* src = (gg < 1024) ? Wth : Wtl;
      const int a = gg & 1023;
      gp[i] = (const char*)(src + (size_t)(n0 + (a >> 2)) * DMODEL + (a & 3) * 8);
      stepb[i] = 64;
    }
    ldso[i] = idx * 512;  // shorts; wave-uniform
  }

  f32x4 c[2][4];
#pragma unroll
  for (int mt = 0; mt < 2; mt++)
#pragma unroll
    for (int nt = 0; nt < 4; nt++) c[mt][nt] = (f32x4){0.f, 0.f, 0.f, 0.f};

  constexpr int NT = DMODEL / 32;  // 16 K-steps

  // prologue: issue loads for t=0 into buffer 0
#pragma unroll
  for (int i = 0; i < 5; i++) GLOAD_LDS16(gp[i], &L[ldso[i]]);

  for (int t = 0; t < NT; t++) {
    __syncthreads();  // tile t resident; buf^1 free of readers
    if (t + 1 < NT) {
      short* dst = &L[((t + 1) & 1) * 20480];
#pragma unroll
      for (int i = 0; i < 5; i++)
        GLOAD_LDS16(gp[i] + (t + 1) * stepb[i], dst + ldso[i]);
    }
    const short* buf = &L[(t & 1) * 20480];
    const float* Af = (const float*)buf;
    short8 ah[2], al[2], bh[4], bl[4];
#pragma unroll
    for (int mt = 0; mt < 2; mt++) {
      const int r = wm + mt * 16 + lane15;
      const f32x4 a0 = *(const f32x4*)&Af[r * 32 + quad * 8];
      const f32x4 a1 = *(const f32x4*)&Af[r * 32 + quad * 8 + 4];
#pragma unroll
      for (int j = 0; j < 4; j++) {
        short x, y;
        bf16_split(a0[j], x, y);
        ah[mt][j] = x;
        al[mt][j] = y;
        bf16_split(a1[j], x, y);
        ah[mt][4 + j] = x;
        al[mt][4 + j] = y;
      }
    }
#pragma unroll
    for (int nt = 0; nt < 4; nt++) {
      const int r = wn + nt * 16 + lane15;
      bh[nt] = *(const short8*)&buf[4096 + r * 32 + quad * 8];
      bl[nt] = *(const short8*)&buf[12288 + r * 32 + quad * 8];
    }
    __builtin_amdgcn_s_setprio(1);
#pragma unroll
    for (int mt = 0; mt < 2; mt++)
#pragma unroll
      for (int nt = 0; nt < 4; nt++) {
        c[mt][nt] = MFMA16(ah[mt], bh[nt], c[mt][nt]);
        c[mt][nt] = MFMA16(ah[mt], bl[nt], c[mt][nt]);
        c[mt][nt] = MFMA16(al[mt], bh[nt], c[mt][nt]);
      }
    __builtin_amdgcn_s_setprio(0);
  }

  // ---- epilogue ----
#pragma unroll
  for (int nt = 0; nt < 4; nt++) {
    const int n = n0 + wn + nt * 16 + lane15;
    const float bb = bias[n];
#pragma unroll
    for (int mt = 0; mt < 2; mt++)
#pragma unroll
      for (int r = 0; r < 4; r++) {
        const int m = m0 + wm + mt * 16 + quad * 4 + r;
        const float val = c[mt][nt][r] + bb;
        if (MODE == 1) {
          const int bidx = m >> 12;
          const int s = m & 4095;
          const int hh = n >> 6;
          const int d = n & 63;
          const size_t off =
              ((size_t)(bidx * NHEAD + hh) * SDIM + s) * DHEAD + d;
          short x, y;
          bf16_split(val, x, y);
          oh[off] = x;
          ol[off] = y;
        } else {
          out[(size_t)m * DMODEL + n] = val;
        }
      }
  }
}

// ---------------------------------------------------------------------------
// V transpose: [B,H,S,D] h/l shorts -> [B,H,D,S]. 64x64 tiles via LDS.
// ---------------------------------------------------------------------------
__global__ __launch_bounds__(256) void vtrans_kernel(
    const short* __restrict__ vh, const short* __restrict__ vl,
    short* __restrict__ vth, short* __restrict__ vtl) {
  __shared__ short Th[64 * 72], Tl[64 * 72];
  const int tid = threadIdx.x;
  const int s0 = blockIdx.x * 64;
  const int h = blockIdx.y;
  const int b = blockIdx.z;
  const size_t base = (size_t)(b * NHEAD + h) * SDIM * DHEAD;

  {
    const int s = tid >> 2;
    const int c = tid & 3;
    const short* srcH = vh + base + (size_t)(s0 + s) * DHEAD + c * 16;
    const short* srcL = vl + base + (size_t)(s0 + s) * DHEAD + c * 16;
    *(short8*)&Th[s * 72 + c * 16] = *(const short8*)srcH;
    *(short8*)&Th[s * 72 + c * 16 + 8] = *(const short8*)(srcH + 8);
    *(short8*)&Tl[s * 72 + c * 16] = *(const short8*)srcL;
    *(short8*)&Tl[s * 72 + c * 16 + 8] = *(const short8*)(srcL + 8);
  }
  __syncthreads();
  {
    const int d = tid & 63;
    const int cw = tid >> 6;
    short8 a0, a1, b0, b1;
#pragma unroll
    for (int i = 0; i < 8; i++) {
      a0[i] = Th[(cw * 16 + i) * 72 + d];
      a1[i] = Th[(cw * 16 + 8 + i) * 72 + d];
      b0[i] = Tl[(cw * 16 + i) * 72 + d];
      b1[i] = Tl[(cw * 16 + 8 + i) * 72 + d];
    }
    short* dstH = vth + base + (size_t)d * SDIM + s0 + cw * 16;
    short* dstL = vtl + base + (size_t)d * SDIM + s0 + cw * 16;
    *(short8*)dstH = a0;
    *(short8*)(dstH + 8) = a1;
    *(short8*)dstL = b0;
    *(short8*)(dstL + 8) = b1;
  }
}

// ---------------------------------------------------------------------------
// Flash attention, bf16x3 MFMA, fixed-shift softmax.
// R3: R1's proven LDS-staged structure (stage K/V once per block, 4 waves
// share it), but QBLK=256 with 64 q-rows per wave (mt=0..3): MFMA per
// staged K/V byte doubles (208 vs 104 MFMA/tile/wave while K/V LDS reads
// stay 32 KB/wave; K-frags hoisted nt-outer, read once). LDS 104 KB ->
// exactly 1 block/CU, grid 256 = 1 block per CU. T14 reg prefetch + raw
// barriers + setprio retained. VGPR budget 512/wave (1 wave/SIMD).
// ---------------------------------------------------------------------------
#define KP 72
#define VP 72
#define PP 68

__global__ __launch_bounds__(256, 1) void flash_attn_kernel(
    const short* __restrict__ qhh, const short* __restrict__ qhl,
    const short* __restrict__ khh, const short* __restrict__ khl,
    const short* __restrict__ vth, const short* __restrict__ vtl,
    const float* __restrict__ mask, float* __restrict__ ctx) {
  __shared__ short Ksh[64 * KP], Ksl[64 * KP];
  __shared__ short Vsh[64 * VP], Vsl[64 * VP];
  __shared__ float Ps[256 * PP];  // 69.6 KB, wave-private rows

  const int tid = threadIdx.x;
  const int lane = tid & 63;
  const int w = tid >> 6;
  const int lane15 = lane & 15;
  const int quad = lane >> 4;

  // Bijective XCD swizzle (256 blocks, 256%8==0): each XCD gets 32
  // consecutive work ids = 2 heads -> K/V L2 locality.
  const int bid = blockIdx.x + 16 * (blockIdx.y + NHEAD * blockIdx.z);
  const int sw = (bid & 7) * 32 + (bid >> 3);
  const int q0 = (sw & 15) * 256;
  const int h = (sw >> 4) & 7;
  const int b = sw >> 7;

  const size_t base = (size_t)(b * NHEAD + h) * SDIM * DHEAD;
  const short* Qh = qhh + base;
  const short* Ql = qhl + base;
  const short* Kh = khh + base;
  const short* Kl = khl + base;
  const short* Vh = vth + base;  // [D][S]
  const short* Vl = vtl + base;
  const float* mb = mask + (size_t)b * SDIM;

  short8 qfh[4][2], qfl[4][2];
#pragma unroll
  for (int mt = 0; mt < 4; mt++) {
    const size_t row = q0 + w * 64 + mt * 16 + lane15;
#pragma unroll
    for (int ks = 0; ks < 2; ks++) {
      qfh[mt][ks] = *(const short8*)(Qh + row * DHEAD + ks * 32 + quad * 8);
      qfl[mt][ks] = *(const short8*)(Ql + row * DHEAD + ks * 32 + quad * 8);
    }
  }

  f32x4 o[4][4];
#pragma unroll
  for (int mt = 0; mt < 4; mt++)
#pragma unroll
    for (int dt = 0; dt < 4; dt++) o[mt][dt] = (f32x4){0.f, 0.f, 0.f, 0.f};
  float lr[4][4];
#pragma unroll
  for (int mt = 0; mt < 4; mt++)
#pragma unroll
    for (int r = 0; r < 4; r++) lr[mt][r] = 0.f;

  short8 onesb;
#pragma unroll
  for (int j = 0; j < 8; j++) onesb[j] = (short)0x3F80;  // bf16 1.0

  const int sr = tid >> 2;
  const int sc = (tid & 3) * 16;

  // prologue: prefetch tile 0 into registers
  short8 rg[8];
  rg[0] = *(const short8*)(Kh + (size_t)sr * DHEAD + sc);
  rg[1] = *(const short8*)(Kh + (size_t)sr * DHEAD + sc + 8);
  rg[2] = *(const short8*)(Kl + (size_t)sr * DHEAD + sc);
  rg[3] = *(const short8*)(Kl + (size_t)sr * DHEAD + sc + 8);
  rg[4] = *(const short8*)(Vh + (size_t)sr * SDIM + sc);
  rg[5] = *(const short8*)(Vh + (size_t)sr * SDIM + sc + 8);
  rg[6] = *(const short8*)(Vl + (size_t)sr * SDIM + sc);
  rg[7] = *(const short8*)(Vl + (size_t)sr * SDIM + sc + 8);

  for (int kt = 0; kt < SDIM / 64; kt++) {
    const int k0 = kt * 64;
    // barrier A: every wave finished reading the previous tile's LDS
    __builtin_amdgcn_s_barrier();
    __builtin_amdgcn_sched_barrier(0);
    *(short8*)&Ksh[sr * KP + sc] = rg[0];
    *(short8*)&Ksh[sr * KP + sc + 8] = rg[1];
    *(short8*)&Ksl[sr * KP + sc] = rg[2];
    *(short8*)&Ksl[sr * KP + sc + 8] = rg[3];
    *(short8*)&Vsh[sr * VP + sc] = rg[4];
    *(short8*)&Vsh[sr * VP + sc + 8] = rg[5];
    *(short8*)&Vsl[sr * VP + sc] = rg[6];
    *(short8*)&Vsl[sr * VP + sc + 8] = rg[7];
    // T14: issue next tile's global loads now; they stay in flight across
    // the raw barrier and land under this tile's compute.
    if (kt + 1 < SDIM / 64) {
      const int k1 = k0 + 64;
      rg[0] = *(const short8*)(Kh + (size_t)(k1 + sr) * DHEAD + sc);
      rg[1] = *(const short8*)(Kh + (size_t)(k1 + sr) * DHEAD + sc + 8);
      rg[2] = *(const short8*)(Kl + (size_t)(k1 + sr) * DHEAD + sc);
      rg[3] = *(const short8*)(Kl + (size_t)(k1 + sr) * DHEAD + sc + 8);
      rg[4] = *(const short8*)(Vh + (size_t)sr * SDIM + k1 + sc);
      rg[5] = *(const short8*)(Vh + (size_t)sr * SDIM + k1 + sc + 8);
      rg[6] = *(const short8*)(Vl + (size_t)sr * SDIM + k1 + sc);
      rg[7] = *(const short8*)(Vl + (size_t)sr * SDIM + k1 + sc + 8);
    }
    float mv[4];
#pragma unroll
    for (int nt = 0; nt < 4; nt++)
      mv[nt] = fmaf(mb[k0 + nt * 16 + lane15], MASKMUL, -M0C);
    // barrier B: LDS writes visible (lgkm only — vmcnt stays outstanding)
    asm volatile("s_waitcnt lgkmcnt(0)" ::: "memory");
    __builtin_amdgcn_s_barrier();
    __builtin_amdgcn_sched_barrier(0);

    // QK^T: K-fragments read once per nt, reused across 4 mt.
    __builtin_amdgcn_s_setprio(1);
#pragma unroll
    for (int nt = 0; nt < 4; nt++) {
      short8 kbh[2], kbl[2];
#pragma unroll
      for (int ks = 0; ks < 2; ks++) {
        const int koff = (nt * 16 + lane15) * KP + ks * 32 + quad * 8;
        kbh[ks] = *(const short8*)&Ksh[koff];
        kbl[ks] = *(const short8*)&Ksl[koff];
      }
#pragma unroll
      for (int mt = 0; mt < 4; mt++) {
        f32x4 acc = (f32x4){0.f, 0.f, 0.f, 0.f};
#pragma unroll
        for (int ks = 0; ks < 2; ks++) {
          acc = MFMA16(qfh[mt][ks], kbh[ks], acc);
          acc = MFMA16(qfh[mt][ks], kbl[ks], acc);
          acc = MFMA16(qfl[mt][ks], kbh[ks], acc);
        }
#pragma unroll
        for (int r = 0; r < 4; r++) {
          const float p = EXP2F(fmaf(acc[r], SCALE2, mv[nt]));
          Ps[(w * 64 + mt * 16 + quad * 4 + r) * PP + nt * 16 + lane15] = p;
        }
      }
    }
    __builtin_amdgcn_s_setprio(0);

    short8 pah[4][2], pal[4][2];
#pragma unroll
    for (int mt = 0; mt < 4; mt++)
#pragma unroll
      for (int kf = 0; kf < 2; kf++) {
        const float* pr =
            &Ps[(w * 64 + mt * 16 + lane15) * PP + kf * 32 + quad * 8];
        const f32x4 p0 = *(const f32x4*)pr;
        const f32x4 p1 = *(const f32x4*)(pr + 4);
        short8 ph, pl;
#pragma unroll
        for (int j = 0; j < 4; j++) {
          short hh, ll;
          bf16_split(p0[j], hh, ll);
          ph[j] = hh;
          pl[j] = ll;
        }
#pragma unroll
        for (int j = 0; j < 4; j++) {
          short hh, ll;
          bf16_split(p1[j], hh, ll);
          ph[4 + j] = hh;
          pl[4 + j] = ll;
        }
        pah[mt][kf] = ph;
        pal[mt][kf] = pl;
      }

    __builtin_amdgcn_s_setprio(1);
#pragma unroll
    for (int mt = 0; mt < 4; mt++) {
      f32x4 racc = (f32x4){0.f, 0.f, 0.f, 0.f};
#pragma unroll
      for (int kf = 0; kf < 2; kf++) {
        racc = MFMA16(pah[mt][kf], onesb, racc);
        racc = MFMA16(pal[mt][kf], onesb, racc);
      }
#pragma unroll
      for (int r = 0; r < 4; r++) lr[mt][r] += racc[r];
    }

#pragma unroll
    for (int dt = 0; dt < 4; dt++)
#pragma unroll
      for (int kf = 0; kf < 2; kf++) {
        const int voff = (dt * 16 + lane15) * VP + kf * 32 + quad * 8;
        const short8 vbh = *(const short8*)&Vsh[voff];
        const short8 vbl = *(const short8*)&Vsl[voff];
#pragma unroll
        for (int mt = 0; mt < 4; mt++) {
          o[mt][dt] = MFMA16(pah[mt][kf], vbh, o[mt][dt]);
          o[mt][dt] = MFMA16(pah[mt][kf], vbl, o[mt][dt]);
          o[mt][dt] = MFMA16(pal[mt][kf], vbh, o[mt][dt]);
        }
      }
    __builtin_amdgcn_s_setprio(0);
  }

  float inv[4][4];
#pragma unroll
  for (int mt = 0; mt < 4; mt++)
#pragma unroll
    for (int r = 0; r < 4; r++) inv[mt][r] = 1.f / lr[mt][r];
#pragma unroll
  for (int mt = 0; mt < 4; mt++)
#pragma unroll
    for (int dt = 0; dt < 4; dt++)
#pragma unroll
      for (int r = 0; r < 4; r++) {
        const int q = q0 + w * 64 + mt * 16 + quad * 4 + r;
        const int col = h * DHEAD + dt * 16 + lane15;
        ctx[((size_t)b * SDIM + q) * DMODEL + col] = o[mt][dt][r] * inv[mt][r];
      }
}

// ---------------------------------------------------------------------------
extern "C" void kernel_launch(void* const* d_in, const int* in_sizes, int n_in,
                              void* d_out, int out_size, void* d_ws,
                              size_t ws_size, hipStream_t stream) {
  const float* q = (const float*)d_in[0];
  const float* k = (const float*)d_in[1];
  const float* v = (const float*)d_in[2];
  const float* mask = (const float*)d_in[3];
  const float* Wq = (const float*)d_in[4];
  const float* bq = (const float*)d_in[5];
  const float* Wk = (const float*)d_in[6];
  const float* bk = (const float*)d_in[7];
  const float* Wv = (const float*)d_in[8];
  const float* bv = (const float*)d_in[9];
  const float* Wo = (const float*)d_in[10];
  const float* bo = (const float*)d_in[11];
  float* out = (float*)d_out;

  char* W = (char*)d_ws;
  const size_t SZB = (size_t)MROWS * DMODEL * sizeof(short);  // 8 MB
  short* q_h = (short*)(W + 0 * SZB);
  short* q_l = (short*)(W + 1 * SZB);
  short* k_h = (short*)(W + 2 * SZB);
  short* k_l = (short*)(W + 3 * SZB);
  short* v_h = (short*)(W + 4 * SZB);
  short* v_l = (short*)(W + 5 * SZB);
  short* vt_h = (short*)(W + 6 * SZB);
  short* vt_l = (short*)(W + 7 * SZB);
  // ctx (fp32, 16 MB) aliases v_h/v_l — dead after vtrans.
  float* ctx = (float*)(W + 4 * SZB);
  const size_t WSZ = (size_t)DMODEL * DMODEL * sizeof(short);  // 512 KB
  char* WT = W + 8 * SZB;
  short* wtq_h = (short*)(WT + 0 * WSZ);
  short* wtq_l = (short*)(WT + 1 * WSZ);
  short* wtk_h = (short*)(WT + 2 * WSZ);
  short* wtk_l = (short*)(WT + 3 * WSZ);
  short* wtv_h = (short*)(WT + 4 * WSZ);
  short* wtv_l = (short*)(WT + 5 * WSZ);
  short* wto_h = (short*)(WT + 6 * WSZ);
  short* wto_l = (short*)(WT + 7 * WSZ);

  wsplit_kernel<<<dim3(DMODEL / 64, DMODEL / 64, 4), 256, 0, stream>>>(
      Wq, Wk, Wv, Wo, wtq_h, wtq_l, wtk_h, wtk_l, wtv_h, wtv_l, wto_h, wto_l);

  const dim3 gp2(MROWS / 64, DMODEL / 256);  // (128, 2)

  proj3_kernel<1><<<gp2, 512, 0, stream>>>(q, wtq_h, wtq_l, bq, nullptr, q_h,
                                           q_l);
  proj3_kernel<1><<<gp2, 512, 0, stream>>>(k, wtk_h, wtk_l, bk, nullptr, k_h,
                                           k_l);
  proj3_kernel<1><<<gp2, 512, 0, stream>>>(v, wtv_h, wtv_l, bv, nullptr, v_h,
                                           v_l);

  vtrans_kernel<<<dim3(SDIM / 64, NHEAD, BDIM), 256, 0, stream>>>(v_h, v_l,
                                                                  vt_h, vt_l);

  flash_attn_kernel<<<dim3(SDIM / 256, NHEAD, BDIM), 256, 0, stream>>>(
      q_h, q_l, k_h, k_l, vt_h, vt_l, mask, ctx);

  proj3_kernel<0><<<gp2, 512, 0, stream>>>(ctx, wto_h, wto_l, bo, out, nullptr,
                                           nullptr);
}

// Round 5
// 368.870 us; speedup vs baseline: 1.7764x; 1.2113x over previous
//
#include <hip/hip_runtime.h>
#include <math.h>

#define BDIM 2
#define SDIM 4096
#define DMODEL 512
#define NHEAD 8
#define DHEAD 64
#define MROWS (BDIM * SDIM)  // 8192

typedef __attribute__((ext_vector_type(8))) short short8;
typedef __attribute__((ext_vector_type(4))) float f32x4;
typedef __attribute__((ext_vector_type(4))) int i32x4;

union S8I4 {
  short8 s;
  i32x4 i;
};

#define MFMA16(a, b, c) __builtin_amdgcn_mfma_f32_16x16x32_bf16((a), (b), (c), 0, 0, 0)
#define EXP2F(x) __builtin_amdgcn_exp2f(x)

#define SCALE2 0.18033688011112042f  // 0.125 * log2(e)
#define MASKMUL -1.442695040e9f      // -1e9 * log2(e)
#define M0C 16.0f                    // fixed softmax shift (2^-M0 cancels in O/l)

#define GLOAD_LDS16(g, l)                                                     \
  __builtin_amdgcn_global_load_lds(                                           \
      (const __attribute__((address_space(1))) void*)(g),                     \
      (__attribute__((address_space(3))) void*)(l), 16, 0, 0)

// Truncation split: x = h + l with h = top 16 bits (exact subtraction).
__device__ inline void bf16_split(float x, short& h, short& l) {
  unsigned u = __float_as_uint(x);
  h = (short)(u >> 16);
  float hf = __uint_as_float(u & 0xffff0000u);
  l = (short)(__float_as_uint(x - hf) >> 16);
}

// Paired split+pack via v_perm: .x = (h1<<16)|h0, .y = (l1<<16)|l0.
// Bitwise identical to bf16_split on each value; 6 VALU per 2 values.
__device__ inline int2 bf16_split_pack(float x0, float x1) {
  const unsigned u0 = __float_as_uint(x0), u1 = __float_as_uint(x1);
  const float d0 = x0 - __uint_as_float(u0 & 0xffff0000u);
  const float d1 = x1 - __uint_as_float(u1 & 0xffff0000u);
  int2 r;
  r.x = __builtin_amdgcn_perm(u1, u0, 0x07060302);
  r.y = __builtin_amdgcn_perm(__float_as_uint(d1), __float_as_uint(d0),
                              0x07060302);
  return r;
}

// ---------------------------------------------------------------------------
// One-shot weight prep: W[k][n] fp32 -> Wt_h[n][k], Wt_l[n][k] bf16 h/l.
// ---------------------------------------------------------------------------
__global__ __launch_bounds__(256) void wsplit_kernel(
    const float* __restrict__ W0, const float* __restrict__ W1,
    const float* __restrict__ W2, const float* __restrict__ W3,
    short* __restrict__ T0h, short* __restrict__ T0l, short* __restrict__ T1h,
    short* __restrict__ T1l, short* __restrict__ T2h, short* __restrict__ T2l,
    short* __restrict__ T3h, short* __restrict__ T3l) {
  __shared__ short Th[64 * 72], Tl[64 * 72];
  const int tid = threadIdx.x;
  const int k0 = blockIdx.x * 64;
  const int n0 = blockIdx.y * 64;
  const int z = blockIdx.z;
  const float* W = (z == 0) ? W0 : (z == 1) ? W1 : (z == 2) ? W2 : W3;
  short* Oh = (z == 0) ? T0h : (z == 1) ? T1h : (z == 2) ? T2h : T3h;
  short* Ol = (z == 0) ? T0l : (z == 1) ? T1l : (z == 2) ? T2l : T3l;

  {
    const int r = tid >> 2;
    const int c16 = (tid & 3) * 16;
    short8 h0, h1, l0, l1;
#pragma unroll
    for (int g = 0; g < 2; g++) {
      const f32x4 a = *(const f32x4*)(W + (size_t)(k0 + r) * DMODEL + n0 + c16 + g * 8);
      const f32x4 b = *(const f32x4*)(W + (size_t)(k0 + r) * DMODEL + n0 + c16 + g * 8 + 4);
      short8& hh = g ? h1 : h0;
      short8& ll = g ? l1 : l0;
#pragma unroll
      for (int j = 0; j < 4; j++) {
        short x, y;
        bf16_split(a[j], x, y);
        hh[j] = x;
        ll[j] = y;
        bf16_split(b[j], x, y);
        hh[4 + j] = x;
        ll[4 + j] = y;
      }
    }
    *(short8*)&Th[r * 72 + c16] = h0;
    *(short8*)&Th[r * 72 + c16 + 8] = h1;
    *(short8*)&Tl[r * 72 + c16] = l0;
    *(short8*)&Tl[r * 72 + c16 + 8] = l1;
  }
  __syncthreads();
  {
    const int n = tid >> 2;
    const int kc = (tid & 3) * 16;
    short8 h0, h1, l0, l1;
#pragma unroll
    for (int i = 0; i < 8; i++) {
      h0[i] = Th[(kc + i) * 72 + n];
      h1[i] = Th[(kc + 8 + i) * 72 + n];
      l0[i] = Tl[(kc + i) * 72 + n];
      l1[i] = Tl[(kc + 8 + i) * 72 + n];
    }
    short* dh = Oh + (size_t)(n0 + n) * DMODEL + k0 + kc;
    short* dl = Ol + (size_t)(n0 + n) * DMODEL + k0 + kc;
    *(short8*)dh = h0;
    *(short8*)(dh + 8) = h1;
    *(short8*)dl = l0;
    *(short8*)(dl + 8) = l1;
  }
}

// ---------------------------------------------------------------------------
// MFMA bf16x3 GEMM: out[M,512] = X[M,512](fp32) @ Wt(split)^T + bias.
// BM=64, BN=256, BK=32, 512 thr = 8 waves (2Mx4N), wave tile 32x64.
// A staged RAW FP32 via global_load_lds, split in-register post-ds_read.
// Runtime mode (wave-uniform): -1 => derive from blockIdx.z (z==2 ? 2 : 1).
//   mode 0: fp32 out[M,DM]                         (output projection)
//   mode 1: bf16 h/l split out in [B,H,S,D]        (q/k projections)
//   mode 2: bf16 h/l split TRANSPOSED [B,H,D,S]    (v projection; vtrans
//           fused via in-kernel LDS re-transpose — no untransposed write)
// QKV merged in one launch: grid.z in {0,1,2} selects X/W/bias/output.
// ---------------------------------------------------------------------------
__global__ __launch_bounds__(512, 2) void proj4_kernel(
    const int mode_sel, const float* __restrict__ X0,
    const float* __restrict__ X1, const float* __restrict__ X2,
    const short* __restrict__ Wth0, const short* __restrict__ Wth1,
    const short* __restrict__ Wth2, const short* __restrict__ Wtl0,
    const short* __restrict__ Wtl1, const short* __restrict__ Wtl2,
    const float* __restrict__ bias0, const float* __restrict__ bias1,
    const float* __restrict__ bias2, float* __restrict__ out,
    short* __restrict__ qoh, short* __restrict__ qol, short* __restrict__ koh,
    short* __restrict__ kol, short* __restrict__ vth, short* __restrict__ vtl) {
  // per buffer (shorts): Af32[64*32 floats]=4096 | Bh[256*32]=8192 | Bl=8192
  __shared__ short L[2 * 20480];  // 80 KB; reused by mode-2 epilogue
  const int tid = threadIdx.x;
  const int lane = tid & 63;
  const int w = tid >> 6;  // 0..7
  const int lane15 = lane & 15;
  const int quad = lane >> 4;
  const int m0 = blockIdx.x * 64;
  const int n0 = blockIdx.y * 256;
  const int z = blockIdx.z;
  const int mode = (mode_sel >= 0) ? mode_sel : (z == 2 ? 2 : 1);
  const float* X = (z == 0) ? X0 : (z == 1) ? X1 : X2;
  const short* Wth = (z == 0) ? Wth0 : (z == 1) ? Wth1 : Wth2;
  const short* Wtl = (z == 0) ? Wtl0 : (z == 1) ? Wtl1 : Wtl2;
  const float* bias = (z == 0) ? bias0 : (z == 1) ? bias1 : bias2;
  short* oh = (z == 0) ? qoh : koh;
  short* ol = (z == 0) ? qol : kol;
  const int wm = (w >> 2) * 32;
  const int wn = (w & 3) * 64;

  // Staging: 2560 16B-chunks/step, 5 per wave. idx<8 -> A (fp32),
  // idx>=8 -> B (bf16 h/l). Per-chunk K-step stride differs (128B vs 64B).
  const char* gp[5];
  int stepb[5], ldso[5];
#pragma unroll
  for (int i = 0; i < 5; i++) {
    const int idx = w * 5 + i;
    if (idx < 8) {  // A: fp32 rows, 8 chunks of 4 floats per 32-k row
      const int g = idx * 64 + lane;
      gp[i] = (const char*)(X + (size_t)(m0 + (g >> 3)) * DMODEL + (g & 7) * 4);
      stepb[i] = 128;
    } else {  // B: rows of Wth/Wtl, 4 chunks of 8 shorts per 32-k row
      const int gg = idx * 64 + lane - 512;
      const short* src = (gg < 1024) ? Wth : Wtl;
      const int a = gg & 1023;
      gp[i] = (const char*)(src + (size_t)(n0 + (a >> 2)) * DMODEL + (a & 3) * 8);
      stepb[i] = 64;
    }
    ldso[i] = idx * 512;  // shorts; wave-uniform
  }

  f32x4 c[2][4];
#pragma unroll
  for (int mt = 0; mt < 2; mt++)
#pragma unroll
    for (int nt = 0; nt < 4; nt++) c[mt][nt] = (f32x4){0.f, 0.f, 0.f, 0.f};

  constexpr int NT = DMODEL / 32;  // 16 K-steps

  // prologue: issue loads for t=0 into buffer 0
#pragma unroll
  for (int i = 0; i < 5; i++) GLOAD_LDS16(gp[i], &L[ldso[i]]);

  for (int t = 0; t < NT; t++) {
    __syncthreads();  // tile t resident; buf^1 free of readers
    if (t + 1 < NT) {
      short* dst = &L[((t + 1) & 1) * 20480];
#pragma unroll
      for (int i = 0; i < 5; i++)
        GLOAD_LDS16(gp[i] + (t + 1) * stepb[i], dst + ldso[i]);
    }
    const short* buf = &L[(t & 1) * 20480];
    const float* Af = (const float*)buf;
    short8 ah[2], al[2], bh[4], bl[4];
#pragma unroll
    for (int mt = 0; mt < 2; mt++) {
      const int r = wm + mt * 16 + lane15;
      const f32x4 a0 = *(const f32x4*)&Af[r * 32 + quad * 8];
      const f32x4 a1 = *(const f32x4*)&Af[r * 32 + quad * 8 + 4];
      S8I4 hh, ll;
      const int2 p0 = bf16_split_pack(a0[0], a0[1]);
      const int2 p1 = bf16_split_pack(a0[2], a0[3]);
      const int2 p2 = bf16_split_pack(a1[0], a1[1]);
      const int2 p3 = bf16_split_pack(a1[2], a1[3]);
      hh.i[0] = p0.x; ll.i[0] = p0.y;
      hh.i[1] = p1.x; ll.i[1] = p1.y;
      hh.i[2] = p2.x; ll.i[2] = p2.y;
      hh.i[3] = p3.x; ll.i[3] = p3.y;
      ah[mt] = hh.s;
      al[mt] = ll.s;
    }
#pragma unroll
    for (int nt = 0; nt < 4; nt++) {
      const int r = wn + nt * 16 + lane15;
      bh[nt] = *(const short8*)&buf[4096 + r * 32 + quad * 8];
      bl[nt] = *(const short8*)&buf[12288 + r * 32 + quad * 8];
    }
    __builtin_amdgcn_s_setprio(1);
#pragma unroll
    for (int mt = 0; mt < 2; mt++)
#pragma unroll
      for (int nt = 0; nt < 4; nt++) {
        c[mt][nt] = MFMA16(ah[mt], bh[nt], c[mt][nt]);
        c[mt][nt] = MFMA16(ah[mt], bl[nt], c[mt][nt]);
        c[mt][nt] = MFMA16(al[mt], bh[nt], c[mt][nt]);
      }
    __builtin_amdgcn_s_setprio(0);
  }

  // ---- epilogue ----
  if (mode == 2) {
    // V: write ONLY the transposed [B,H,D,S] h/l via LDS re-transpose.
    __syncthreads();  // all compute reads of L done
    short* Lh = L;            // [256][72]
    short* Ll = L + 18432;    // [256][72]
#pragma unroll
    for (int nt = 0; nt < 4; nt++) {
      const int n = wn + nt * 16 + lane15;  // 0..255 within tile
      const float bb = bias[n0 + n];
#pragma unroll
      for (int mt = 0; mt < 2; mt++)
#pragma unroll
        for (int r = 0; r < 4; r++) {
          const int m = wm + mt * 16 + quad * 4 + r;  // 0..63 within tile
          short x, y;
          bf16_split(c[mt][nt][r] + bb, x, y);
          Lh[n * 72 + m] = x;
          Ll[n * 72 + m] = y;
        }
    }
    __syncthreads();
    const int row = tid >> 1;  // n within tile, 0..255
    const int half = tid & 1;
    const int n = n0 + row;
    const int hh = n >> 6, d = n & 63;
    const int bidx = m0 >> 12, s0 = m0 & 4095;
    const size_t tbase = ((size_t)(bidx * NHEAD + hh)) * SDIM * DHEAD +
                         (size_t)d * SDIM + s0 + half * 32;
#pragma unroll
    for (int i = 0; i < 4; i++) {
      *(short8*)(vth + tbase + i * 8) = *(const short8*)&Lh[row * 72 + half * 32 + i * 8];
      *(short8*)(vtl + tbase + i * 8) = *(const short8*)&Ll[row * 72 + half * 32 + i * 8];
    }
    return;
  }

#pragma unroll
  for (int nt = 0; nt < 4; nt++) {
    const int n = n0 + wn + nt * 16 + lane15;
    const float bb = bias[n];
#pragma unroll
    for (int mt = 0; mt < 2; mt++)
#pragma unroll
      for (int r = 0; r < 4; r++) {
        const int m = m0 + wm + mt * 16 + quad * 4 + r;
        const float val = c[mt][nt][r] + bb;
        if (mode == 1) {
          const int bidx = m >> 12;
          const int s = m & 4095;
          const int hh = n >> 6;
          const int d = n & 63;
          const size_t off =
              ((size_t)(bidx * NHEAD + hh) * SDIM + s) * DHEAD + d;
          short x, y;
          bf16_split(val, x, y);
          oh[off] = x;
          ol[off] = y;
        } else {
          out[(size_t)m * DMODEL + n] = val;
        }
      }
  }
}

// ---------------------------------------------------------------------------
// Flash attention, bf16x3 MFMA, fixed-shift softmax.
// R5 = R1's validated 2-blocks/CU structure (LDS-staged K/V, T14 register
// prefetch, raw barriers, setprio) + three shaves:
//   (a) K-fragments hoisted nt-outer: 16 instead of 32 ds_read_b128/wave/tile
//   (b) P bf16 split via paired v_perm pack (6 VALU / 2 values, bit-identical)
//   (c) bijective XCD swizzle: one head-pair per XCD (FETCH 139->~25 MB).
// ---------------------------------------------------------------------------
#define KP 72
#define VP 72
#define PP 68

__global__ __launch_bounds__(256, 2) void flash_attn_kernel(
    const short* __restrict__ qhh, const short* __restrict__ qhl,
    const short* __restrict__ khh, const short* __restrict__ khl,
    const short* __restrict__ vth, const short* __restrict__ vtl,
    const float* __restrict__ mask, float* __restrict__ ctx) {
  __shared__ short Ksh[64 * KP], Ksl[64 * KP];
  __shared__ short Vsh[64 * VP], Vsl[64 * VP];
  __shared__ float Ps[128 * PP];

  const int tid = threadIdx.x;
  const int lane = tid & 63;
  const int w = tid >> 6;
  const int lane15 = lane & 15;
  const int quad = lane >> 4;

  // Bijective XCD swizzle (nwg=512, 512%8==0): blocks on one XCD cover one
  // (b, head-pair) -> its 4 MB of K/V h+l stays in that XCD's L2.
  const int bid = blockIdx.x + 32 * (blockIdx.y + NHEAD * blockIdx.z);
  const int sw = (bid & 7) * 64 + (bid >> 3);
  const int q0 = (sw & 31) * 128;
  const int h = (sw >> 5) & 7;
  const int b = sw >> 8;

  const size_t base = (size_t)(b * NHEAD + h) * SDIM * DHEAD;
  const short* Qh = qhh + base;
  const short* Ql = qhl + base;
  const short* Kh = khh + base;
  const short* Kl = khl + base;
  const short* Vh = vth + base;  // [D][S]
  const short* Vl = vtl + base;
  const float* mb = mask + (size_t)b * SDIM;

  short8 qfh[2][2], qfl[2][2];
#pragma unroll
  for (int mt = 0; mt < 2; mt++) {
    const size_t row = q0 + w * 32 + mt * 16 + lane15;
#pragma unroll
    for (int ks = 0; ks < 2; ks++) {
      qfh[mt][ks] = *(const short8*)(Qh + row * DHEAD + ks * 32 + quad * 8);
      qfl[mt][ks] = *(const short8*)(Ql + row * DHEAD + ks * 32 + quad * 8);
    }
  }

  f32x4 o[2][4];
#pragma unroll
  for (int mt = 0; mt < 2; mt++)
#pragma unroll
    for (int dt = 0; dt < 4; dt++) o[mt][dt] = (f32x4){0.f, 0.f, 0.f, 0.f};
  float lr[2][4];
#pragma unroll
  for (int mt = 0; mt < 2; mt++)
#pragma unroll
    for (int r = 0; r < 4; r++) lr[mt][r] = 0.f;

  short8 onesb;
#pragma unroll
  for (int j = 0; j < 8; j++) onesb[j] = (short)0x3F80;  // bf16 1.0

  const int sr = tid >> 2;
  const int sc = (tid & 3) * 16;

  // prologue: prefetch tile 0 into registers
  short8 rg[8];
  rg[0] = *(const short8*)(Kh + (size_t)sr * DHEAD + sc);
  rg[1] = *(const short8*)(Kh + (size_t)sr * DHEAD + sc + 8);
  rg[2] = *(const short8*)(Kl + (size_t)sr * DHEAD + sc);
  rg[3] = *(const short8*)(Kl + (size_t)sr * DHEAD + sc + 8);
  rg[4] = *(const short8*)(Vh + (size_t)sr * SDIM + sc);
  rg[5] = *(const short8*)(Vh + (size_t)sr * SDIM + sc + 8);
  rg[6] = *(const short8*)(Vl + (size_t)sr * SDIM + sc);
  rg[7] = *(const short8*)(Vl + (size_t)sr * SDIM + sc + 8);

  for (int kt = 0; kt < SDIM / 64; kt++) {
    const int k0 = kt * 64;
    // barrier A: every wave finished reading the previous tile's LDS
    __builtin_amdgcn_s_barrier();
    __builtin_amdgcn_sched_barrier(0);
    *(short8*)&Ksh[sr * KP + sc] = rg[0];
    *(short8*)&Ksh[sr * KP + sc + 8] = rg[1];
    *(short8*)&Ksl[sr * KP + sc] = rg[2];
    *(short8*)&Ksl[sr * KP + sc + 8] = rg[3];
    *(short8*)&Vsh[sr * VP + sc] = rg[4];
    *(short8*)&Vsh[sr * VP + sc + 8] = rg[5];
    *(short8*)&Vsl[sr * VP + sc] = rg[6];
    *(short8*)&Vsl[sr * VP + sc + 8] = rg[7];
    // T14: issue next tile's global loads now; they stay in flight across
    // the raw barrier and land under this tile's compute.
    if (kt + 1 < SDIM / 64) {
      const int k1 = k0 + 64;
      rg[0] = *(const short8*)(Kh + (size_t)(k1 + sr) * DHEAD + sc);
      rg[1] = *(const short8*)(Kh + (size_t)(k1 + sr) * DHEAD + sc + 8);
      rg[2] = *(const short8*)(Kl + (size_t)(k1 + sr) * DHEAD + sc);
      rg[3] = *(const short8*)(Kl + (size_t)(k1 + sr) * DHEAD + sc + 8);
      rg[4] = *(const short8*)(Vh + (size_t)sr * SDIM + k1 + sc);
      rg[5] = *(const short8*)(Vh + (size_t)sr * SDIM + k1 + sc + 8);
      rg[6] = *(const short8*)(Vl + (size_t)sr * SDIM + k1 + sc);
      rg[7] = *(const short8*)(Vl + (size_t)sr * SDIM + k1 + sc + 8);
    }
    float mv[4];
#pragma unroll
    for (int nt = 0; nt < 4; nt++)
      mv[nt] = fmaf(mb[k0 + nt * 16 + lane15], MASKMUL, -M0C);
    // barrier B: LDS writes visible (lgkm only — vmcnt stays outstanding)
    asm volatile("s_waitcnt lgkmcnt(0)" ::: "memory");
    __builtin_amdgcn_s_barrier();
    __builtin_amdgcn_sched_barrier(0);

    // QK^T: K-fragments read once per nt, reused across both mt.
    __builtin_amdgcn_s_setprio(1);
#pragma unroll
    for (int nt = 0; nt < 4; nt++) {
      short8 kbh[2], kbl[2];
#pragma unroll
      for (int ks = 0; ks < 2; ks++) {
        const int koff = (nt * 16 + lane15) * KP + ks * 32 + quad * 8;
        kbh[ks] = *(const short8*)&Ksh[koff];
        kbl[ks] = *(const short8*)&Ksl[koff];
      }
#pragma unroll
      for (int mt = 0; mt < 2; mt++) {
        f32x4 acc = (f32x4){0.f, 0.f, 0.f, 0.f};
#pragma unroll
        for (int ks = 0; ks < 2; ks++) {
          acc = MFMA16(qfh[mt][ks], kbh[ks], acc);
          acc = MFMA16(qfh[mt][ks], kbl[ks], acc);
          acc = MFMA16(qfl[mt][ks], kbh[ks], acc);
        }
#pragma unroll
        for (int r = 0; r < 4; r++) {
          const float p = EXP2F(fmaf(acc[r], SCALE2, mv[nt]));
          Ps[(w * 32 + mt * 16 + quad * 4 + r) * PP + nt * 16 + lane15] = p;
        }
      }
    }
    __builtin_amdgcn_s_setprio(0);

    // P split+pack via v_perm (bit-identical to bf16_split per element).
    short8 pah[2][2], pal[2][2];
#pragma unroll
    for (int mt = 0; mt < 2; mt++)
#pragma unroll
      for (int kf = 0; kf < 2; kf++) {
        const float* pr =
            &Ps[(w * 32 + mt * 16 + lane15) * PP + kf * 32 + quad * 8];
        const f32x4 p0 = *(const f32x4*)pr;
        const f32x4 p1 = *(const f32x4*)(pr + 4);
        S8I4 ph, pl;
        const int2 r0 = bf16_split_pack(p0[0], p0[1]);
        const int2 r1 = bf16_split_pack(p0[2], p0[3]);
        const int2 r2 = bf16_split_pack(p1[0], p1[1]);
        const int2 r3 = bf16_split_pack(p1[2], p1[3]);
        ph.i[0] = r0.x; pl.i[0] = r0.y;
        ph.i[1] = r1.x; pl.i[1] = r1.y;
        ph.i[2] = r2.x; pl.i[2] = r2.y;
        ph.i[3] = r3.x; pl.i[3] = r3.y;
        pah[mt][kf] = ph.s;
        pal[mt][kf] = pl.s;
      }

    __builtin_amdgcn_s_setprio(1);
#pragma unroll
    for (int mt = 0; mt < 2; mt++) {
      f32x4 racc = (f32x4){0.f, 0.f, 0.f, 0.f};
#pragma unroll
      for (int kf = 0; kf < 2; kf++) {
        racc = MFMA16(pah[mt][kf], onesb, racc);
        racc = MFMA16(pal[mt][kf], onesb, racc);
      }
#pragma unroll
      for (int r = 0; r < 4; r++) lr[mt][r] += racc[r];
    }

#pragma unroll
    for (int dt = 0; dt < 4; dt++)
#pragma unroll
      for (int kf = 0; kf < 2; kf++) {
        const int voff = (dt * 16 + lane15) * VP + kf * 32 + quad * 8;
        const short8 vbh = *(const short8*)&Vsh[voff];
        const short8 vbl = *(const short8*)&Vsl[voff];
#pragma unroll
        for (int mt = 0; mt < 2; mt++) {
          o[mt][dt] = MFMA16(pah[mt][kf], vbh, o[mt][dt]);
          o[mt][dt] = MFMA16(pah[mt][kf], vbl, o[mt][dt]);
          o[mt][dt] = MFMA16(pal[mt][kf], vbh, o[mt][dt]);
        }
      }
    __builtin_amdgcn_s_setprio(0);
  }

  float inv[2][4];
#pragma unroll
  for (int mt = 0; mt < 2; mt++)
#pragma unroll
    for (int r = 0; r < 4; r++) inv[mt][r] = 1.f / lr[mt][r];
#pragma unroll
  for (int mt = 0; mt < 2; mt++)
#pragma unroll
    for (int dt = 0; dt < 4; dt++)
#pragma unroll
      for (int r = 0; r < 4; r++) {
        const int q = q0 + w * 32 + mt * 16 + quad * 4 + r;
        const int col = h * DHEAD + dt * 16 + lane15;
        ctx[((size_t)b * SDIM + q) * DMODEL + col] = o[mt][dt][r] * inv[mt][r];
      }
}

// ---------------------------------------------------------------------------
extern "C" void kernel_launch(void* const* d_in, const int* in_sizes, int n_in,
                              void* d_out, int out_size, void* d_ws,
                              size_t ws_size, hipStream_t stream) {
  const float* q = (const float*)d_in[0];
  const float* k = (const float*)d_in[1];
  const float* v = (const float*)d_in[2];
  const float* mask = (const float*)d_in[3];
  const float* Wq = (const float*)d_in[4];
  const float* bq = (const float*)d_in[5];
  const float* Wk = (const float*)d_in[6];
  const float* bk = (const float*)d_in[7];
  const float* Wv = (const float*)d_in[8];
  const float* bv = (const float*)d_in[9];
  const float* Wo = (const float*)d_in[10];
  const float* bo = (const float*)d_in[11];
  float* out = (float*)d_out;

  char* W = (char*)d_ws;
  const size_t SZB = (size_t)MROWS * DMODEL * sizeof(short);  // 8 MB
  short* q_h = (short*)(W + 0 * SZB);
  short* q_l = (short*)(W + 1 * SZB);
  short* k_h = (short*)(W + 2 * SZB);
  short* k_l = (short*)(W + 3 * SZB);
  short* vt_h = (short*)(W + 4 * SZB);
  short* vt_l = (short*)(W + 5 * SZB);
  float* ctx = (float*)(W + 6 * SZB);  // fp32, 16 MB = 2*SZB
  const size_t WSZ = (size_t)DMODEL * DMODEL * sizeof(short);  // 512 KB
  char* WT = W + 8 * SZB;
  short* wtq_h = (short*)(WT + 0 * WSZ);
  short* wtq_l = (short*)(WT + 1 * WSZ);
  short* wtk_h = (short*)(WT + 2 * WSZ);
  short* wtk_l = (short*)(WT + 3 * WSZ);
  short* wtv_h = (short*)(WT + 4 * WSZ);
  short* wtv_l = (short*)(WT + 5 * WSZ);
  short* wto_h = (short*)(WT + 6 * WSZ);
  short* wto_l = (short*)(WT + 7 * WSZ);

  wsplit_kernel<<<dim3(DMODEL / 64, DMODEL / 64, 4), 256, 0, stream>>>(
      Wq, Wk, Wv, Wo, wtq_h, wtq_l, wtk_h, wtk_l, wtv_h, wtv_l, wto_h, wto_l);

  // Merged Q/K/V projections (z selects); V writes transposed only.
  proj4_kernel<<<dim3(MROWS / 64, DMODEL / 256, 3), 512, 0, stream>>>(
      -1, q, k, v, wtq_h, wtk_h, wtv_h, wtq_l, wtk_l, wtv_l, bq, bk, bv,
      nullptr, q_h, q_l, k_h, k_l, vt_h, vt_l);

  flash_attn_kernel<<<dim3(SDIM / 128, NHEAD, BDIM), 256, 0, stream>>>(
      q_h, q_l, k_h, k_l, vt_h, vt_l, mask, ctx);

  // Output projection (mode 0), X = ctx.
  proj4_kernel<<<dim3(MROWS / 64, DMODEL / 256, 1), 512, 0, stream>>>(
      0, ctx, nullptr, nullptr, wto_h, nullptr, nullptr, wto_l, nullptr,
      nullptr, bo, nullptr, nullptr, out, nullptr, nullptr, nullptr, nullptr,
      nullptr, nullptr);
}